// Round 2
// baseline (202.772 us; speedup 1.0000x reference)
//
#include <hip/hip_runtime.h>
#include <hip/hip_bf16.h>
#include <stdint.h>

// Problem constants (fixed by reference)
#define T_TASKS 8
#define DM      1024
#define HID     1024
#define NC      100
#define NCP     128
#define BATCH   8192
#define MPAD    9216      // 8192 + 8*128 worst-case 128-aligned padding
#define MTILES  72

typedef __bf16 bf16x8 __attribute__((ext_vector_type(8)));
typedef float  f32x4  __attribute__((ext_vector_type(4)));
typedef unsigned int u32;
#define GAS __attribute__((address_space(1)))
#define LAS __attribute__((address_space(3)))

__device__ __forceinline__ unsigned short f2bf(float f) {
  __hip_bfloat16 h = __float2bfloat16(f);
  return __builtin_bit_cast(unsigned short, h);
}

// ---------------------------------------------------------------------------
// init: zero d_out (for split-K atomics), perm = -1, gmeta (gcnt+gcur) = 0.
// ---------------------------------------------------------------------------
__global__ void init_k(float* __restrict__ out, int* __restrict__ perm,
                       int* __restrict__ gmeta) {
  const int gid = blockIdx.x * 256 + threadIdx.x;
  const uint4 z  = {0u, 0u, 0u, 0u};
  const uint4 m1 = {0xFFFFFFFFu, 0xFFFFFFFFu, 0xFFFFFFFFu, 0xFFFFFFFFu};
  uint4* o4 = (uint4*)out;
  for (int i = gid; i < (BATCH * NC) / 4; i += 512 * 256) o4[i] = z;
  uint4* p4 = (uint4*)perm;
  for (int i = gid; i < MPAD / 4; i += 512 * 256) p4[i] = m1;
  if (gid < 16) gmeta[gid] = 0;
}

// ---------------------------------------------------------------------------
// count: per-block LDS histogram -> 8 global atomics. grid 32 x 256.
// ---------------------------------------------------------------------------
__global__ void count_k(const int* __restrict__ task_id, int* __restrict__ gmeta) {
  __shared__ int h[T_TASKS];
  const int tid = threadIdx.x;
  if (tid < T_TASKS) h[tid] = 0;
  __syncthreads();
  const int r = blockIdx.x * 256 + tid;
  atomicAdd(&h[task_id[r]], 1);
  __syncthreads();
  if (tid < T_TASKS) atomicAdd(&gmeta[tid], h[tid]);
}

// ---------------------------------------------------------------------------
// scatter: starts from complete gcnt; per-block local slots (LDS atomic
// return value) + one range reservation per task per block. grid 32 x 256.
// ---------------------------------------------------------------------------
__global__ void scatter_k(const int* __restrict__ task_id, int* __restrict__ gmeta,
                          int* __restrict__ perm, int* __restrict__ starts) {
  __shared__ int h[T_TASKS];
  __shared__ int base[T_TASKS];
  __shared__ int sst[T_TASKS + 1];
  const int tid = threadIdx.x;
  if (tid < T_TASKS) h[tid] = 0;
  if (tid == 0) {
    int off = 0;
    for (int t = 0; t < T_TASKS; ++t) {
      sst[t] = off;
      off += (gmeta[t] + 127) & ~127;
    }
    sst[T_TASKS] = off;
  }
  __syncthreads();
  const int r = blockIdx.x * 256 + tid;
  const int t = task_id[r];
  const int slot = atomicAdd(&h[t], 1);
  __syncthreads();
  if (tid < T_TASKS) base[tid] = atomicAdd(&gmeta[8 + tid], h[tid]);
  __syncthreads();
  perm[sst[t] + base[t] + slot] = r;
  if (blockIdx.x == 0 && tid <= T_TASKS) starts[tid] = sst[tid];
}

// ---------------------------------------------------------------------------
// convert x fp32 -> bf16 (no permutation). grid 4096 x 256, 8 elem/thread.
// ---------------------------------------------------------------------------
__global__ void convert_x(const float* __restrict__ x, unsigned short* __restrict__ XB) {
  const size_t i = ((size_t)(blockIdx.x * 256 + threadIdx.x)) * 8;
  const float4 f0 = *(const float4*)(x + i);
  const float4 f1 = *(const float4*)(x + i + 4);
  union { uint4 v; unsigned short s[8]; } o;
  o.s[0] = f2bf(f0.x); o.s[1] = f2bf(f0.y); o.s[2] = f2bf(f0.z); o.s[3] = f2bf(f0.w);
  o.s[4] = f2bf(f1.x); o.s[5] = f2bf(f1.y); o.s[6] = f2bf(f1.z); o.s[7] = f2bf(f1.w);
  *(uint4*)(XB + i) = o.v;
}

// ---------------------------------------------------------------------------
// W1 [t][d][h] fp32 -> W1T [t][h][d] bf16  (LDS-tiled 64x64)
// ---------------------------------------------------------------------------
__global__ void transpose_w1(const float* __restrict__ W1,
                             unsigned short* __restrict__ W1T) {
  __shared__ unsigned short tile[64][65];
  const int t  = blockIdx.z;
  const int d0 = blockIdx.x * 64;
  const int h0 = blockIdx.y * 64;
  const int tid = threadIdx.x;
  const float* src = W1 + (size_t)t * DM * HID;
  unsigned short* dst = W1T + (size_t)t * HID * DM;
#pragma unroll
  for (int i = 0; i < 16; ++i) {
    int idx = tid + 256 * i;
    int ld = idx >> 6, lh = idx & 63;            // read coalesced in h
    tile[lh][ld] = f2bf(src[(size_t)(d0 + ld) * HID + h0 + lh]);
  }
  __syncthreads();
#pragma unroll
  for (int i = 0; i < 16; ++i) {
    int idx = tid + 256 * i;
    int lh = idx >> 6, ld = idx & 63;            // write coalesced in d
    dst[(size_t)(h0 + lh) * DM + d0 + ld] = tile[lh][ld];
  }
}

// ---------------------------------------------------------------------------
// W2 [t][h][c<100] fp32 -> W2T [t][c<128][h] bf16 (pad cols w/ 0)
// ---------------------------------------------------------------------------
__global__ void transpose_w2(const float* __restrict__ W2,
                             unsigned short* __restrict__ W2T) {
  __shared__ unsigned short tile[64][65];
  const int t  = blockIdx.z;
  const int c0 = blockIdx.x * 64;
  const int h0 = blockIdx.y * 64;
  const int tid = threadIdx.x;
  const float* src = W2 + (size_t)t * HID * NC;
  unsigned short* dst = W2T + (size_t)t * NCP * HID;
#pragma unroll
  for (int i = 0; i < 16; ++i) {
    int idx = tid + 256 * i;
    int lh = idx >> 6, lc = idx & 63;            // read coalesced in c
    int c = c0 + lc;
    float f = (c < NC) ? src[(size_t)(h0 + lh) * NC + c] : 0.f;
    tile[lc][lh] = f2bf(f);
  }
  __syncthreads();
#pragma unroll
  for (int i = 0; i < 16; ++i) {
    int idx = tid + 256 * i;
    int lc = idx >> 6, lh = idx & 63;            // write coalesced in h
    dst[(size_t)(c0 + lc) * HID + h0 + lh] = tile[lc][lh];
  }
}

// ---------------------------------------------------------------------------
// GEMM core, global_load_lds(width=16) staging + XOR-swizzled unpadded LDS.
// Block = 256 thr = 4 waves (2x2); wave = 64x64 = 4x4 of 16x16x32 bf16 MFMA.
// BK=64. LDS chunk (row, j) holds global 16B chunk (row, j ^ (row&7)) so
// ds_read_b128 fragment reads are 2-way bank aliased (free, m136) while the
// global_load_lds dest stays lane-ordered contiguous (wave-uniform rule).
// LAYER1: A rows gathered via perm (pads clamp to row 0, discarded later);
//         epilogue +b1, ReLU, bf16 store to HB.
// LAYER2: A = HB rows direct; split-K over blockIdx.y (K/4 = 256 each);
//         epilogue unsafeAtomicAdd to out via perm scatter, +b2 on chunk 0.
// ---------------------------------------------------------------------------
template <int NTOT, bool LAYER2>
__global__ __launch_bounds__(256, 2) void gemm_k(
    const unsigned short* __restrict__ Abuf,   // XB [8192][1024] or HB [MPAD][1024]
    const unsigned short* __restrict__ BT,     // [T][NTOT][1024] bf16
    const float* __restrict__ bias,            // [T][HID] or [T][NC]
    const int* __restrict__ starts,            // [9]
    const int* __restrict__ perm,              // [MPAD]
    unsigned short* __restrict__ Hout,         // layer1 out (bf16)
    float* __restrict__ Out)                   // layer2 out (fp32, atomic)
{
  __shared__ __align__(16) unsigned short As[128 * 64];
  __shared__ __align__(16) unsigned short Bs[128 * 64];
  const int tid = threadIdx.x;
  const int p0  = blockIdx.x * 128;
  const int tn0 = LAYER2 ? 0 : blockIdx.y * 128;
  const int kbeg = LAYER2 ? blockIdx.y * 256 : 0;
  const int kend = LAYER2 ? kbeg + 256 : 1024;

  int task = 0;
#pragma unroll
  for (int t = 1; t < T_TASKS; ++t)
    if (p0 >= starts[t]) task = t;

  const int wave = tid >> 6;
  const int lane = tid & 63;
  const int wm   = (wave >> 1) * 64;
  const int wn   = (wave & 1) * 64;
  const int lr   = lane & 15;
  const int quad = lane >> 4;

  // Staging geometry: chunk c = tid + 256*i covers 1024 16B chunks per tile.
  // row = c>>3 = (tid>>3) + 32*i; source k-chunk = (c&7) ^ (row&7) (XOR swizzle).
  const int crow = tid >> 3;
  const int kc   = (tid & 7) ^ (crow & 7);
  const unsigned short* pA[4];
  const unsigned short* pB[4];
  const unsigned short* Bg = BT + ((size_t)task * NTOT + tn0) * 1024;
#pragma unroll
  for (int i = 0; i < 4; ++i) {
    const int row = crow + 32 * i;
    int ar;
    if (LAYER2) {
      ar = p0 + row;
    } else {
      ar = perm[p0 + row];
      if (ar < 0) ar = 0;                 // pad rows: garbage, discarded at scatter
    }
    pA[i] = Abuf + (size_t)ar * 1024 + kc * 8;
    pB[i] = Bg + (size_t)row * 1024 + kc * 8;
  }

  f32x4 acc[4][4];
#pragma unroll
  for (int i = 0; i < 4; ++i)
#pragma unroll
    for (int j = 0; j < 4; ++j) acc[i][j] = (f32x4){0.f, 0.f, 0.f, 0.f};

  const int sw0 = quad ^ (lr & 7);        // swizzled chunk col for kk=0
  const int sw1 = (4 + quad) ^ (lr & 7);  // swizzled chunk col for kk=32

  for (int k0 = kbeg; k0 < kend; k0 += 64) {
#pragma unroll
    for (int i = 0; i < 4; ++i) {
      __builtin_amdgcn_global_load_lds((const GAS u32*)(pA[i] + k0),
                                       (LAS u32*)&As[(tid + 256 * i) * 8], 16, 0, 0);
      __builtin_amdgcn_global_load_lds((const GAS u32*)(pB[i] + k0),
                                       (LAS u32*)&Bs[(tid + 256 * i) * 8], 16, 0, 0);
    }
    __syncthreads();
    {
      bf16x8 a[4], b[4];
#pragma unroll
      for (int i = 0; i < 4; ++i)
        a[i] = *(const bf16x8*)&As[((wm + i * 16 + lr) * 8 + sw0) * 8];
#pragma unroll
      for (int j = 0; j < 4; ++j)
        b[j] = *(const bf16x8*)&Bs[((wn + j * 16 + lr) * 8 + sw0) * 8];
#pragma unroll
      for (int i = 0; i < 4; ++i)
#pragma unroll
        for (int j = 0; j < 4; ++j)
          acc[i][j] = __builtin_amdgcn_mfma_f32_16x16x32_bf16(a[i], b[j], acc[i][j], 0, 0, 0);
#pragma unroll
      for (int i = 0; i < 4; ++i)
        a[i] = *(const bf16x8*)&As[((wm + i * 16 + lr) * 8 + sw1) * 8];
#pragma unroll
      for (int j = 0; j < 4; ++j)
        b[j] = *(const bf16x8*)&Bs[((wn + j * 16 + lr) * 8 + sw1) * 8];
#pragma unroll
      for (int i = 0; i < 4; ++i)
#pragma unroll
        for (int j = 0; j < 4; ++j)
          acc[i][j] = __builtin_amdgcn_mfma_f32_16x16x32_bf16(a[i], b[j], acc[i][j], 0, 0, 0);
    }
    __syncthreads();
  }

  // Epilogue. C/D layout: col = lane&15, row = quad*4 + reg  [verified m89]
  if (!LAYER2) {
    const float* bv = bias + (size_t)task * HID;
#pragma unroll
    for (int i = 0; i < 4; ++i) {
#pragma unroll
      for (int r = 0; r < 4; ++r) {
        const int row = p0 + wm + i * 16 + quad * 4 + r;
#pragma unroll
        for (int j = 0; j < 4; ++j) {
          const int col = tn0 + wn + j * 16 + lr;
          float v = acc[i][j][r] + bv[col];
          v = v > 0.f ? v : 0.f;
          Hout[(size_t)row * HID + col] = f2bf(v);
        }
      }
    }
  } else {
    const float* bv = bias + (size_t)task * NC;
    const bool addb = (kbeg == 0);
#pragma unroll
    for (int i = 0; i < 4; ++i) {
#pragma unroll
      for (int r = 0; r < 4; ++r) {
        const int prow = p0 + wm + i * 16 + quad * 4 + r;
        const int orig = perm[prow];
        if (orig < 0) continue;
#pragma unroll
        for (int j = 0; j < 4; ++j) {
          const int col = wn + j * 16 + lr;
          if (col < NC) {
            float v = acc[i][j][r];
            if (addb) v += bv[col];
            unsafeAtomicAdd(&Out[(size_t)orig * NC + col], v);
          }
        }
      }
    }
  }
}

// ---------------------------------------------------------------------------
// Workspace layout (bytes):
//   perm   int[9216]            @ 0           (36864)
//   gmeta  int[16]              @ 36864       (gcnt[8] + gcur[8])
//   starts int[9]               @ 36928
//   XB     bf16[8192*1024]      @ 65536       (16777216)
//   W1T    bf16[8*1024*1024]    @ 16842752    (16777216)
//   W2T    bf16[8*128*1024]     @ 33619968    (2097152)
//   HB     bf16[9216*1024]      @ 35717120    (18874368)
//   total 54591488 (~52 MB)
// ---------------------------------------------------------------------------
extern "C" void kernel_launch(void* const* d_in, const int* in_sizes, int n_in,
                              void* d_out, int out_size, void* d_ws, size_t ws_size,
                              hipStream_t stream) {
  const float* x       = (const float*)d_in[0];
  const int*   task_id = (const int*)d_in[1];
  const float* W1      = (const float*)d_in[2];
  const float* b1      = (const float*)d_in[3];
  const float* W2      = (const float*)d_in[4];
  const float* b2      = (const float*)d_in[5];
  float* out = (float*)d_out;

  char* ws = (char*)d_ws;
  int* perm   = (int*)(ws + 0);
  int* gmeta  = (int*)(ws + 36864);
  int* starts = (int*)(ws + 36928);
  unsigned short* XB  = (unsigned short*)(ws + 65536);
  unsigned short* W1T = (unsigned short*)(ws + 16842752);
  unsigned short* W2T = (unsigned short*)(ws + 33619968);
  unsigned short* HB  = (unsigned short*)(ws + 35717120);

  init_k<<<512, 256, 0, stream>>>(out, perm, gmeta);
  count_k<<<32, 256, 0, stream>>>(task_id, gmeta);
  scatter_k<<<32, 256, 0, stream>>>(task_id, gmeta, perm, starts);
  convert_x<<<4096, 256, 0, stream>>>(x, XB);
  transpose_w1<<<dim3(16, 16, T_TASKS), 256, 0, stream>>>(W1, W1T);
  transpose_w2<<<dim3(2, 16, T_TASKS), 256, 0, stream>>>(W2, W2T);
  gemm_k<HID, false><<<dim3(MTILES, HID / 128), 256, 0, stream>>>(
      XB, W1T, b1, starts, perm, HB, nullptr);
  gemm_k<NCP, true><<<dim3(MTILES, 4), 256, 0, stream>>>(
      HB, W2T, b2, starts, perm, nullptr, out);
}